// Round 11
// baseline (2551.535 us; speedup 1.0000x reference)
//
#include <hip/hip_runtime.h>
#include <cstdint>
#include <cstddef>

typedef _Float16 f16x8 __attribute__((ext_vector_type(8)));
typedef _Float16 f16x4 __attribute__((ext_vector_type(4)));
typedef float floatx4 __attribute__((ext_vector_type(4)));

#define NROIS 1000
#define PD    12544   // 256*49 = fc1 K
#define KFC   1024    // fc2/heads K
#define NLOC  324
#define NSC   81
#define NH    405
#define NBLK  1024    // grid size; 4 blocks/CU x 256 CUs, co-residency by construction

// ---- workspace layout v5 (float offsets), no live aliasing ----------------
#define OFF_T2    0u          // half-units within fT
#define OFF_T3    16777216u
#define OFF_T4    20971520u
#define OFF_T5    22020096u
#define OFF_FT    0u          // fp16 [0, 11,141,120) floats
#define OFF_POOL  11141120u
#define OFF_W1T   17563648u
#define OFF_PART1 23986176u   // 8 x 1,048,576 fp32 (fc1); reused as part2
#define OFF_FC1   32374784u
#define OFF_W2T   32899072u
#define OFF_WHT   33423360u
#define OFF_FC2   33685504u
#define OFF_PART2 23986176u   // fc2: 8 x 1M ; heads: 16 x 512K (both fit 8.39M)

// ---- software grid barrier -------------------------------------------------
// Monotonic ticket counter (zero-init at module load; window arithmetic means
// no reset needed across launches). All NBLK blocks are co-resident
// (LDS 28.7KB -> <=5/CU, launch_bounds(256,4) -> VGPR<=128 -> 4/CU; grid =
// 4 x 256 exactly), so the spin cannot deadlock.
__device__ unsigned int g_ticket = 0;

__device__ __forceinline__ void grid_barrier(int tid)
{
    __syncthreads();
    __threadfence();                     // release: L2 writeback (agent scope)
    if (tid == 0) {
        const unsigned int t = __hip_atomic_fetch_add(
            &g_ticket, 1u, __ATOMIC_ACQ_REL, __HIP_MEMORY_SCOPE_AGENT);
        const unsigned int target = (t / NBLK + 1u) * NBLK;
        while (__hip_atomic_load(&g_ticket, __ATOMIC_ACQUIRE,
                                 __HIP_MEMORY_SCOPE_AGENT) < target)
            __builtin_amdgcn_s_sleep(8);
    }
    __syncthreads();
    __threadfence();                     // acquire: L2 invalidate (agent scope)
}

// ===========================================================================
// Phase subroutines (operate on the block's 28 KB LDS union)
// ===========================================================================

__device__ __forceinline__ void transpose_unit(
    int u, const float* __restrict__ f2, const float* __restrict__ f3,
    const float* __restrict__ f4, const float* __restrict__ f5,
    _Float16* __restrict__ fT, char* smemc, int tid)
{
    float (*tile)[65] = reinterpret_cast<float (*)[65]>(smemc);
    const int g4 = tid & 15, pr = tid >> 4;

    int bx = u % 1360;
    const int c0 = (u / 1360) * 64;
    const float* src; _Float16* dst; int P;
    if (bx < 1024)      {            src = f2; dst = fT + OFF_T2; P = 65536; }
    else if (bx < 1280) { bx -= 1024; src = f3; dst = fT + OFF_T3; P = 16384; }
    else if (bx < 1344) { bx -= 1280; src = f4; dst = fT + OFF_T4; P = 4096; }
    else                { bx -= 1344; src = f5; dst = fT + OFF_T5; P = 1024; }
    const int p0 = bx * 64;

#pragma unroll
    for (int k = 0; k < 4; ++k) {
        const int ch = pr + k * 16;
        const float4 v = *reinterpret_cast<const float4*>(
            &src[(size_t)(c0 + ch) * P + p0 + g4 * 4]);
        tile[ch][g4 * 4 + 0] = v.x;
        tile[ch][g4 * 4 + 1] = v.y;
        tile[ch][g4 * 4 + 2] = v.z;
        tile[ch][g4 * 4 + 3] = v.w;
    }
    __syncthreads();
#pragma unroll
    for (int k = 0; k < 4; ++k) {
        const int px = pr + k * 16;
        union { _Float16 h[4]; uint2 u2; } pk;
        pk.h[0] = (_Float16)tile[g4 * 4 + 0][px];
        pk.h[1] = (_Float16)tile[g4 * 4 + 1][px];
        pk.h[2] = (_Float16)tile[g4 * 4 + 2][px];
        pk.h[3] = (_Float16)tile[g4 * 4 + 3][px];
        *reinterpret_cast<uint2*>(&dst[(size_t)(p0 + px) * 256 + c0 + g4 * 4]) = pk.u2;
    }
}

__device__ __forceinline__ void w1_unit(
    int v, const float* __restrict__ W1, _Float16* __restrict__ W1T,
    char* smemc, int tid)
{
    float (*tile)[65] = reinterpret_cast<float (*)[65]>(smemc);
    const int g4 = tid & 15, pr = tid >> 4;
    const int p0 = (v % 196) * 64;
    const int n0 = (v / 196) * 64;
#pragma unroll
    for (int k = 0; k < 4; ++k) {
        const int r    = pr + k * 16;
        const int pp   = p0 + r;
        const int ksrc = (pp & 255) * 49 + (pp >> 8);
        const float4 w = *reinterpret_cast<const float4*>(
            &W1[(size_t)ksrc * 1024 + n0 + g4 * 4]);
        tile[r][g4 * 4 + 0] = w.x;
        tile[r][g4 * 4 + 1] = w.y;
        tile[r][g4 * 4 + 2] = w.z;
        tile[r][g4 * 4 + 3] = w.w;
    }
    __syncthreads();
#pragma unroll
    for (int k = 0; k < 4; ++k) {
        const int nr = pr + k * 16;
        union { _Float16 h[4]; uint2 u2; } pk;
        pk.h[0] = (_Float16)tile[g4 * 4 + 0][nr];
        pk.h[1] = (_Float16)tile[g4 * 4 + 1][nr];
        pk.h[2] = (_Float16)tile[g4 * 4 + 2][nr];
        pk.h[3] = (_Float16)tile[g4 * 4 + 3][nr];
        *reinterpret_cast<uint2*>(&W1T[(size_t)(n0 + nr) * PD + p0 + g4 * 4]) = pk.u2;
    }
}

__device__ __forceinline__ void w2_unit(
    int v, const float* __restrict__ W2, _Float16* __restrict__ W2T,
    char* smemc, int tid)
{
    float (*tile)[65] = reinterpret_cast<float (*)[65]>(smemc);
    const int g4 = tid & 15, pr = tid >> 4;
    const int p0 = (v % 16) * 64;   // k block
    const int n0 = (v / 16) * 64;   // n block
#pragma unroll
    for (int k = 0; k < 4; ++k) {
        const int r = pr + k * 16;
        const float4 w = *reinterpret_cast<const float4*>(
            &W2[(size_t)(p0 + r) * 1024 + n0 + g4 * 4]);
        tile[r][g4 * 4 + 0] = w.x;
        tile[r][g4 * 4 + 1] = w.y;
        tile[r][g4 * 4 + 2] = w.z;
        tile[r][g4 * 4 + 3] = w.w;
    }
    __syncthreads();
#pragma unroll
    for (int k = 0; k < 4; ++k) {
        const int nr = pr + k * 16;
        union { _Float16 h[4]; uint2 u2; } pk;
        pk.h[0] = (_Float16)tile[g4 * 4 + 0][nr];
        pk.h[1] = (_Float16)tile[g4 * 4 + 1][nr];
        pk.h[2] = (_Float16)tile[g4 * 4 + 2][nr];
        pk.h[3] = (_Float16)tile[g4 * 4 + 3][nr];
        *reinterpret_cast<uint2*>(&W2T[(size_t)(n0 + nr) * KFC + p0 + g4 * 4]) = pk.u2;
    }
}

__device__ __forceinline__ void wh_unit(
    int v, const float* __restrict__ Wloc, const float* __restrict__ Wsc,
    _Float16* __restrict__ WhT, char* smemc, int tid)
{
    float (*tile)[65] = reinterpret_cast<float (*)[65]>(smemc);
    const int g4 = tid & 15, pr = tid >> 4;
    const int p0 = (v % 16) * 64;   // k block
    const int n0 = (v / 16) * 64;   // n block (0..7)
    const int col = tid & 63;
    const int r0  = tid >> 6;
#pragma unroll
    for (int r = r0; r < 64; r += 4) {
        const int pp = p0 + r;
        const int n  = n0 + col;
        float w = 0.0f;
        if (n < NLOC)    w = Wloc[(size_t)pp * NLOC + n];
        else if (n < NH) w = Wsc[(size_t)pp * NSC + (n - NLOC)];
        tile[r][col] = w;
    }
    __syncthreads();
#pragma unroll
    for (int k = 0; k < 4; ++k) {
        const int nr = pr + k * 16;
        union { _Float16 h[4]; uint2 u2; } pk;
        pk.h[0] = (_Float16)tile[g4 * 4 + 0][nr];
        pk.h[1] = (_Float16)tile[g4 * 4 + 1][nr];
        pk.h[2] = (_Float16)tile[g4 * 4 + 2][nr];
        pk.h[3] = (_Float16)tile[g4 * 4 + 3][nr];
        *reinterpret_cast<uint2*>(&WhT[(size_t)(n0 + nr) * KFC + p0 + g4 * 4]) = pk.u2;
    }
}

__device__ __forceinline__ void pool_unit(
    int u, const _Float16* __restrict__ fT, const float* __restrict__ rois,
    const int* __restrict__ img_size, _Float16* __restrict__ pooledH,
    char* smemc, int tid)
{
    const int roi  = u / 7;
    const int ph   = u % 7;
    const int lane = tid & 63;
    const int wave = tid >> 6;
    const int syy  = wave >> 1;
    const int sxp  = wave & 1;

    const float y1 = rois[roi * 4 + 0];
    const float x1 = rois[roi * 4 + 1];
    const float y2 = rois[roi * 4 + 2];
    const float x2 = rois[roi * 4 + 3];

    const float hh = y2 - y1 + 1.0f;
    const float ww = x2 - x1 + 1.0f;
    float lvlf = floorf(logf(sqrtf(hh * ww) / 224.0f) / 0.693147f + 4.0f);
    lvlf = fminf(fmaxf(lvlf, 2.0f), 5.0f);
    const int lvl = (int)lvlf;

    const _Float16* f;
    int H;
    if (lvl == 2)      { f = fT + OFF_T2; H = 256; }
    else if (lvl == 3) { f = fT + OFF_T3; H = 128; }
    else if (lvl == 4) { f = fT + OFF_T4; H = 64;  }
    else               { f = fT + OFF_T5; H = 32;  }
    const int W = H;

    const float imh = (float)img_size[0] - 1.0f;
    const float imw = (float)img_size[1] - 1.0f;
    const float r0 = y1 * (float)(H - 1) / imh;
    const float r1 = x1 * (float)(W - 1) / imw;
    const float r2 = y2 * (float)(H - 1) / imh;
    const float r3 = x2 * (float)(W - 1) / imw;
    const float hs  = (r2 - r0) * (1.0f / 14.0f);
    const float wst = (r3 - r1) * (1.0f / 14.0f);

    const float cy = ((float)(ph * 2 + syy) + 0.5f) * hs + r0;
    const float fy = floorf(cy);
    int   iu  = (int)fy;
    int   idn = (int)ceilf(cy);
    const float ly = cy - fy;
    iu  = min(max(iu, 0),  H - 1);
    idn = min(max(idn, 0), H - 1);
    const float wU = 1.0f - ly, wD = ly;
    const f16x4* rowU = (const f16x4*)(f + (size_t)(iu  * W) * 256);
    const f16x4* rowD = (const f16x4*)(f + (size_t)(idn * W) * 256);

    float4 (*red)[7][64] = reinterpret_cast<float4 (*)[7][64]>(smemc);   // 28 KB

#pragma unroll
    for (int pw = 0; pw < 7; ++pw) {
        const int sx = pw * 2 + sxp;
        const float cx = ((float)sx + 0.5f) * wst + r1;
        const float fx = floorf(cx);
        int   il = (int)fx;
        int   ir = (int)ceilf(cx);
        const float lx = cx - fx;
        il = min(max(il, 0), W - 1);
        ir = min(max(ir, 0), W - 1);

        const f16x4 h00 = rowU[il * 64 + lane];
        const f16x4 h01 = rowU[ir * 64 + lane];
        const f16x4 h10 = rowD[il * 64 + lane];
        const f16x4 h11 = rowD[ir * 64 + lane];
        const float lxm = 1.0f - lx;
        float4 v;
        v.x = ((float)h00.x * lxm + (float)h01.x * lx) * wU + ((float)h10.x * lxm + (float)h11.x * lx) * wD;
        v.y = ((float)h00.y * lxm + (float)h01.y * lx) * wU + ((float)h10.y * lxm + (float)h11.y * lx) * wD;
        v.z = ((float)h00.z * lxm + (float)h01.z * lx) * wU + ((float)h10.z * lxm + (float)h11.z * lx) * wD;
        v.w = ((float)h00.w * lxm + (float)h01.w * lx) * wU + ((float)h10.w * lxm + (float)h11.w * lx) * wD;
        red[wave][pw][lane] = v;
    }
    __syncthreads();

    for (int idx = tid; idx < 448; idx += 256) {
        const int pw = idx >> 6, cg = idx & 63;
        const float4 a = red[0][pw][cg];
        const float4 b = red[1][pw][cg];
        const float4 c = red[2][pw][cg];
        const float4 d = red[3][pw][cg];
        union { _Float16 h[4]; uint2 v2; } pk;
        pk.h[0] = (_Float16)fmaxf(fmaxf(a.x, b.x), fmaxf(c.x, d.x));
        pk.h[1] = (_Float16)fmaxf(fmaxf(a.y, b.y), fmaxf(c.y, d.y));
        pk.h[2] = (_Float16)fmaxf(fmaxf(a.z, b.z), fmaxf(c.z, d.z));
        pk.h[3] = (_Float16)fmaxf(fmaxf(a.w, b.w), fmaxf(c.w, d.w));
        _Float16* outp = pooledH + (size_t)roi * PD + (ph * 7 + pw) * 256 + cg * 4;
        *reinterpret_cast<uint2*>(outp) = pk.v2;
    }
}

// fp16 MFMA GEMM unit (proven 64x128/BK=64 structure). One block-unit.
__device__ __forceinline__ void gemm_unit(
    const unsigned short* __restrict__ A, const unsigned short* __restrict__ B,
    float* __restrict__ partial, int K2, int N,
    int z, int nz, int ny, int mz, char* smemc, int tid)
{
    unsigned short* As = reinterpret_cast<unsigned short*>(smemc);          // 8 KB
    unsigned short* Bs = reinterpret_cast<unsigned short*>(smemc + 8192);   // 16 KB

    const int lane = tid & 63;
    const int wave = tid >> 6;

    const int totalSteps = K2 >> 6;
    const int q = totalSteps / nz, r = totalSteps % nz;
    const int myStart = z * q + min(z, r);
    const int mySteps = q + (z < r ? 1 : 0);

    const int n0 = ny * 128;
    const int m0 = mz * 64;

    const int rIn  = lane >> 3;
    const int cSrc = (lane & 7) ^ rIn;
    const int mrow = lane & 15, quad = lane >> 4;

    floatx4 acc[8];
#pragma unroll
    for (int j = 0; j < 8; ++j)
        acc[j] = (floatx4){0.f, 0.f, 0.f, 0.f};

    for (int s = 0; s < mySteps; ++s) {
        const int k0 = (myStart + s) * 64;
#pragma unroll
        for (int qq = 0; qq < 2; ++qq) {
            const int rowBase = wave * 16 + qq * 8;
            const unsigned short* ga =
                A + (size_t)(m0 + rowBase + rIn) * K2 + k0 + cSrc * 8;
            __builtin_amdgcn_global_load_lds(
                (const __attribute__((address_space(1))) void*)ga,
                (__attribute__((address_space(3))) void*)&As[rowBase * 64], 16, 0, 0);
        }
#pragma unroll
        for (int qq = 0; qq < 4; ++qq) {
            const int rowBase = wave * 32 + qq * 8;
            const unsigned short* gb =
                B + (size_t)(n0 + rowBase + rIn) * K2 + k0 + cSrc * 8;
            __builtin_amdgcn_global_load_lds(
                (const __attribute__((address_space(1))) void*)gb,
                (__attribute__((address_space(3))) void*)&Bs[rowBase * 64], 16, 0, 0);
        }
        __syncthreads();

#pragma unroll
        for (int ks = 0; ks < 2; ++ks) {
            const int ra = wave * 16 + mrow;
            const int ca = ((ks * 4 + quad) ^ (ra & 7)) * 8;
            const f16x8 aF = *reinterpret_cast<const f16x8*>(&As[ra * 64 + ca]);
#pragma unroll
            for (int j = 0; j < 8; ++j) {
                const int rb = j * 16 + mrow;
                const int cb = ((ks * 4 + quad) ^ (rb & 7)) * 8;
                const f16x8 bF = *reinterpret_cast<const f16x8*>(&Bs[rb * 64 + cb]);
                acc[j] = __builtin_amdgcn_mfma_f32_16x16x32_f16(aF, bF, acc[j], 0, 0, 0);
            }
        }
        __syncthreads();
    }

    // slice stride: 16 m-blocks x 64 rows = 1024 rows x N
    float* p = partial + (size_t)z * (size_t)(16 * 64) * N;
    const int row = m0 + wave * 16 + quad * 4;
#pragma unroll
    for (int j = 0; j < 8; ++j) {
        const int col = n0 + j * 16 + mrow;
#pragma unroll
        for (int rr = 0; rr < 4; ++rr)
            p[(size_t)(row + rr) * N + col] = acc[j][rr];
    }
}

__device__ __forceinline__ void red_fc_unit(
    int b, const float* __restrict__ partial, const float* __restrict__ bias,
    _Float16* __restrict__ outH, int nz, int tid)
{
    const int i4 = b * 256 + tid;
    const int off = i4 * 4;
    const int n = off & 1023;
    float4 acc = *reinterpret_cast<const float4*>(partial + off);
    for (int z = 1; z < nz; ++z) {
        const float4 v = *reinterpret_cast<const float4*>(
            partial + (size_t)z * 1024 * 1024 + off);
        acc.x += v.x; acc.y += v.y; acc.z += v.z; acc.w += v.w;
    }
    const float4 bv = *reinterpret_cast<const float4*>(bias + n);
    union { _Float16 h[4]; uint2 u2; } pk;
    pk.h[0] = (_Float16)fmaxf(acc.x + bv.x, 0.f);
    pk.h[1] = (_Float16)fmaxf(acc.y + bv.y, 0.f);
    pk.h[2] = (_Float16)fmaxf(acc.z + bv.z, 0.f);
    pk.h[3] = (_Float16)fmaxf(acc.w + bv.w, 0.f);
    *reinterpret_cast<uint2*>(outH + off) = pk.u2;
}

__device__ __forceinline__ void red_heads_unit(
    int m, const float* __restrict__ partial, const float* __restrict__ bloc,
    const float* __restrict__ bsc, float* __restrict__ out0,
    float* __restrict__ out1, int nz, int tid)
{
    for (int n = tid; n < NH; n += 256) {
        float s = 0.f;
        for (int z = 0; z < nz; ++z)
            s += partial[(size_t)z * 1024 * 512 + (size_t)m * 512 + n];
        if (n < NLOC) out0[(size_t)m * NLOC + n] = s + bloc[n];
        else          out1[(size_t)m * NSC + (n - NLOC)] = s + bsc[n - NLOC];
    }
}

// ===========================================================================
// Mega kernel: whole pipeline, one NORMAL launch, 1024 blocks x 256,
// software ticket barrier between phases.
// ===========================================================================
__global__ __launch_bounds__(256, 4) void mega_kernel(
    const float* __restrict__ f2, const float* __restrict__ f3,
    const float* __restrict__ f4, const float* __restrict__ f5,
    const float* __restrict__ rois, const int* __restrict__ img,
    const float* __restrict__ W1, const float* __restrict__ b1,
    const float* __restrict__ W2, const float* __restrict__ b2,
    const float* __restrict__ Wloc, const float* __restrict__ bloc,
    const float* __restrict__ Wsc, const float* __restrict__ bsc,
    float* __restrict__ out, float* __restrict__ ws)
{
    __shared__ __align__(16) char smem[28672];
    const int tid = threadIdx.x;
    const int nb  = gridDim.x;      // 1024

    _Float16* fT     = (_Float16*)(ws + OFF_FT);
    _Float16* pooled = (_Float16*)(ws + OFF_POOL);
    _Float16* w1t    = (_Float16*)(ws + OFF_W1T);
    float*    part1  = ws + OFF_PART1;
    float*    part2  = ws + OFF_PART2;
    _Float16* fc1    = (_Float16*)(ws + OFF_FC1);
    _Float16* w2t    = (_Float16*)(ws + OFF_W2T);
    _Float16* wht    = (_Float16*)(ws + OFF_WHT);
    _Float16* fc2    = (_Float16*)(ws + OFF_FC2);
    float*    out0   = out;
    float*    out1   = out + (size_t)NROIS * NLOC;

    // ---- Phase A: transpose (5440) + W1 (3136) + W2 (256) + Wh (128) ----
    for (int u = blockIdx.x; u < 8960; u += nb) {
        if (u < 5440)      transpose_unit(u, f2, f3, f4, f5, fT, smem, tid);
        else if (u < 8576) w1_unit(u - 5440, W1, w1t, smem, tid);
        else if (u < 8832) w2_unit(u - 8576, W2, w2t, smem, tid);
        else               wh_unit(u - 8832, Wloc, Wsc, wht, smem, tid);
        __syncthreads();
    }
    grid_barrier(tid);

    // ---- Phase B: ROI pool (7000 units) ----
    for (int u = blockIdx.x; u < 7000; u += nb) {
        pool_unit(u, fT, rois, img, pooled, smem, tid);
        __syncthreads();
    }
    grid_barrier(tid);

    // ---- Phase C: fc1 GEMM (z=8, ny=8, mz=16) = 1024 units exact ----
    {
        const int b = blockIdx.x;
        gemm_unit((const unsigned short*)pooled, (const unsigned short*)w1t,
                  part1, PD, 1024, b & 7, 8, (b >> 3) & 7, b >> 6, smem, tid);
    }
    grid_barrier(tid);

    // ---- Phase D: red1 -> fc1 ----
    red_fc_unit(blockIdx.x, part1, b1, fc1, 8, tid);
    grid_barrier(tid);

    // ---- Phase E: fc2 GEMM (z=8, ny=8, mz=16) ----
    {
        const int b = blockIdx.x;
        gemm_unit((const unsigned short*)fc1, (const unsigned short*)w2t,
                  part2, KFC, 1024, b & 7, 8, (b >> 3) & 7, b >> 6, smem, tid);
    }
    grid_barrier(tid);

    // ---- Phase F: red2 -> fc2 ----
    red_fc_unit(blockIdx.x, part2, b2, fc2, 8, tid);
    grid_barrier(tid);

    // ---- Phase G: heads GEMM (z=16, ny=4, mz=16), N=512 ----
    {
        const int b = blockIdx.x;
        gemm_unit((const unsigned short*)fc2, (const unsigned short*)wht,
                  part2, KFC, 512, b & 15, 16, (b >> 4) & 3, b >> 6, smem, tid);
    }
    grid_barrier(tid);

    // ---- Phase H: heads reduction ----
    if (blockIdx.x < NROIS)
        red_heads_unit(blockIdx.x, part2, bloc, bsc, out0, out1, 16, tid);
}

// ---------------------------------------------------------------------------
extern "C" void kernel_launch(void* const* d_in, const int* in_sizes, int n_in,
                              void* d_out, int out_size, void* d_ws, size_t ws_size,
                              hipStream_t stream)
{
    const float* f2   = (const float*)d_in[0];
    const float* f3   = (const float*)d_in[1];
    const float* f4   = (const float*)d_in[2];
    const float* f5   = (const float*)d_in[3];
    const float* rois = (const float*)d_in[4];
    const int*   img  = (const int*)d_in[5];
    const float* W1   = (const float*)d_in[6];
    const float* b1   = (const float*)d_in[7];
    const float* W2   = (const float*)d_in[8];
    const float* b2   = (const float*)d_in[9];
    const float* Wloc = (const float*)d_in[10];
    const float* bloc = (const float*)d_in[11];
    const float* Wsc  = (const float*)d_in[12];
    const float* bsc  = (const float*)d_in[13];
    float* out = (float*)d_out;
    float* ws  = (float*)d_ws;

    mega_kernel<<<dim3(NBLK), dim3(256), 0, stream>>>(
        f2, f3, f4, f5, rois, img, W1, b1, W2, b2,
        Wloc, bloc, Wsc, bsc, out, ws);
}

// Round 12
// 1538.340 us; speedup vs baseline: 1.6586x; 1.6586x over previous
//
#include <hip/hip_runtime.h>
#include <cstdint>
#include <cstddef>

typedef _Float16 f16x8 __attribute__((ext_vector_type(8)));
typedef _Float16 f16x4 __attribute__((ext_vector_type(4)));
typedef float floatx4 __attribute__((ext_vector_type(4)));

#define NROIS 1000
#define PD    12544   // 256*49 = fc1 K
#define KFC   1024    // fc2/heads K
#define NLOC  324
#define NSC   81
#define NH    405
#define NBLK  1024    // 4 blocks/CU x 256 CUs; co-residency by construction

// ---- workspace layout v5 (float offsets), no live aliasing ----------------
#define OFF_T2    0u          // half-units within fT
#define OFF_T3    16777216u
#define OFF_T4    20971520u
#define OFF_T5    22020096u
#define OFF_FT    0u          // fp16 [0, 11,141,120) floats
#define OFF_POOL  11141120u
#define OFF_W1T   17563648u
#define OFF_PART1 23986176u   // 8 x 1,048,576 fp32 (fc1); reused as part2
#define OFF_FC1   32374784u
#define OFF_W2T   32899072u
#define OFF_WHT   33423360u
#define OFF_FC2   33685504u
#define OFF_PART2 23986176u   // fc2: 8 x 1M ; heads: 16 x 512K (both fit 8.39M)

// ---- software grid barrier -------------------------------------------------
// Monotonic ticket counter (zero-init; window arithmetic survives multiple
// launches without reset). All NBLK blocks co-resident: LDS 28.7KB (<=5/CU),
// launch_bounds(256,4) (VGPR<=128 -> 4/CU), grid = 4 x 256 exactly.
//
// ROUND-11 LESSON: __threadfence() is a cache-WIDE L2 wb/inv op on gfx9xx.
// Executed per-thread (512K times/barrier) it serialized the whole chip
// (2463us, HBM 182 GB/s). __syncthreads() already drains each thread's
// stores to the local L2 (compiler emits s_waitcnt vmcnt(0) before
// s_barrier), so ONE fence per block provides the XCD-L2 writeback /
// invalidate. Poll with s_sleep(64) (~1.7us) to avoid spin contention.
__device__ unsigned int g_ticket = 0;

__device__ __forceinline__ void grid_barrier(int tid)
{
    __syncthreads();                     // all block stores drained to local L2
    if (tid == 0) {
        __threadfence();                 // release: one cache-wide L2 writeback
        const unsigned int t = __hip_atomic_fetch_add(
            &g_ticket, 1u, __ATOMIC_ACQ_REL, __HIP_MEMORY_SCOPE_AGENT);
        const unsigned int target = (t / NBLK + 1u) * NBLK;
        while (__hip_atomic_load(&g_ticket, __ATOMIC_ACQUIRE,
                                 __HIP_MEMORY_SCOPE_AGENT) < target)
            __builtin_amdgcn_s_sleep(64);    // ~4k cycles between polls
        __threadfence();                 // acquire: one cache-wide L2 inv
    }
    __syncthreads();
}

// ===========================================================================
// Phase subroutines (operate on the block's 28 KB LDS union)
// ===========================================================================

__device__ __forceinline__ void transpose_unit(
    int u, const float* __restrict__ f2, const float* __restrict__ f3,
    const float* __restrict__ f4, const float* __restrict__ f5,
    _Float16* __restrict__ fT, char* smemc, int tid)
{
    float (*tile)[65] = reinterpret_cast<float (*)[65]>(smemc);
    const int g4 = tid & 15, pr = tid >> 4;

    int bx = u % 1360;
    const int c0 = (u / 1360) * 64;
    const float* src; _Float16* dst; int P;
    if (bx < 1024)      {            src = f2; dst = fT + OFF_T2; P = 65536; }
    else if (bx < 1280) { bx -= 1024; src = f3; dst = fT + OFF_T3; P = 16384; }
    else if (bx < 1344) { bx -= 1280; src = f4; dst = fT + OFF_T4; P = 4096; }
    else                { bx -= 1344; src = f5; dst = fT + OFF_T5; P = 1024; }
    const int p0 = bx * 64;

#pragma unroll
    for (int k = 0; k < 4; ++k) {
        const int ch = pr + k * 16;
        const float4 v = *reinterpret_cast<const float4*>(
            &src[(size_t)(c0 + ch) * P + p0 + g4 * 4]);
        tile[ch][g4 * 4 + 0] = v.x;
        tile[ch][g4 * 4 + 1] = v.y;
        tile[ch][g4 * 4 + 2] = v.z;
        tile[ch][g4 * 4 + 3] = v.w;
    }
    __syncthreads();
#pragma unroll
    for (int k = 0; k < 4; ++k) {
        const int px = pr + k * 16;
        union { _Float16 h[4]; uint2 u2; } pk;
        pk.h[0] = (_Float16)tile[g4 * 4 + 0][px];
        pk.h[1] = (_Float16)tile[g4 * 4 + 1][px];
        pk.h[2] = (_Float16)tile[g4 * 4 + 2][px];
        pk.h[3] = (_Float16)tile[g4 * 4 + 3][px];
        *reinterpret_cast<uint2*>(&dst[(size_t)(p0 + px) * 256 + c0 + g4 * 4]) = pk.u2;
    }
}

__device__ __forceinline__ void w1_unit(
    int v, const float* __restrict__ W1, _Float16* __restrict__ W1T,
    char* smemc, int tid)
{
    float (*tile)[65] = reinterpret_cast<float (*)[65]>(smemc);
    const int g4 = tid & 15, pr = tid >> 4;
    const int p0 = (v % 196) * 64;
    const int n0 = (v / 196) * 64;
#pragma unroll
    for (int k = 0; k < 4; ++k) {
        const int r    = pr + k * 16;
        const int pp   = p0 + r;
        const int ksrc = (pp & 255) * 49 + (pp >> 8);
        const float4 w = *reinterpret_cast<const float4*>(
            &W1[(size_t)ksrc * 1024 + n0 + g4 * 4]);
        tile[r][g4 * 4 + 0] = w.x;
        tile[r][g4 * 4 + 1] = w.y;
        tile[r][g4 * 4 + 2] = w.z;
        tile[r][g4 * 4 + 3] = w.w;
    }
    __syncthreads();
#pragma unroll
    for (int k = 0; k < 4; ++k) {
        const int nr = pr + k * 16;
        union { _Float16 h[4]; uint2 u2; } pk;
        pk.h[0] = (_Float16)tile[g4 * 4 + 0][nr];
        pk.h[1] = (_Float16)tile[g4 * 4 + 1][nr];
        pk.h[2] = (_Float16)tile[g4 * 4 + 2][nr];
        pk.h[3] = (_Float16)tile[g4 * 4 + 3][nr];
        *reinterpret_cast<uint2*>(&W1T[(size_t)(n0 + nr) * PD + p0 + g4 * 4]) = pk.u2;
    }
}

__device__ __forceinline__ void w2_unit(
    int v, const float* __restrict__ W2, _Float16* __restrict__ W2T,
    char* smemc, int tid)
{
    float (*tile)[65] = reinterpret_cast<float (*)[65]>(smemc);
    const int g4 = tid & 15, pr = tid >> 4;
    const int p0 = (v % 16) * 64;   // k block
    const int n0 = (v / 16) * 64;   // n block
#pragma unroll
    for (int k = 0; k < 4; ++k) {
        const int r = pr + k * 16;
        const float4 w = *reinterpret_cast<const float4*>(
            &W2[(size_t)(p0 + r) * 1024 + n0 + g4 * 4]);
        tile[r][g4 * 4 + 0] = w.x;
        tile[r][g4 * 4 + 1] = w.y;
        tile[r][g4 * 4 + 2] = w.z;
        tile[r][g4 * 4 + 3] = w.w;
    }
    __syncthreads();
#pragma unroll
    for (int k = 0; k < 4; ++k) {
        const int nr = pr + k * 16;
        union { _Float16 h[4]; uint2 u2; } pk;
        pk.h[0] = (_Float16)tile[g4 * 4 + 0][nr];
        pk.h[1] = (_Float16)tile[g4 * 4 + 1][nr];
        pk.h[2] = (_Float16)tile[g4 * 4 + 2][nr];
        pk.h[3] = (_Float16)tile[g4 * 4 + 3][nr];
        *reinterpret_cast<uint2*>(&W2T[(size_t)(n0 + nr) * KFC + p0 + g4 * 4]) = pk.u2;
    }
}

__device__ __forceinline__ void wh_unit(
    int v, const float* __restrict__ Wloc, const float* __restrict__ Wsc,
    _Float16* __restrict__ WhT, char* smemc, int tid)
{
    float (*tile)[65] = reinterpret_cast<float (*)[65]>(smemc);
    const int g4 = tid & 15, pr = tid >> 4;
    const int p0 = (v % 16) * 64;   // k block
    const int n0 = (v / 16) * 64;   // n block (0..7)
    const int col = tid & 63;
    const int r0  = tid >> 6;
#pragma unroll
    for (int r = r0; r < 64; r += 4) {
        const int pp = p0 + r;
        const int n  = n0 + col;
        float w = 0.0f;
        if (n < NLOC)    w = Wloc[(size_t)pp * NLOC + n];
        else if (n < NH) w = Wsc[(size_t)pp * NSC + (n - NLOC)];
        tile[r][col] = w;
    }
    __syncthreads();
#pragma unroll
    for (int k = 0; k < 4; ++k) {
        const int nr = pr + k * 16;
        union { _Float16 h[4]; uint2 u2; } pk;
        pk.h[0] = (_Float16)tile[g4 * 4 + 0][nr];
        pk.h[1] = (_Float16)tile[g4 * 4 + 1][nr];
        pk.h[2] = (_Float16)tile[g4 * 4 + 2][nr];
        pk.h[3] = (_Float16)tile[g4 * 4 + 3][nr];
        *reinterpret_cast<uint2*>(&WhT[(size_t)(n0 + nr) * KFC + p0 + g4 * 4]) = pk.u2;
    }
}

__device__ __forceinline__ void pool_unit(
    int u, const _Float16* __restrict__ fT, const float* __restrict__ rois,
    const int* __restrict__ img_size, _Float16* __restrict__ pooledH,
    char* smemc, int tid)
{
    const int roi  = u / 7;
    const int ph   = u % 7;
    const int lane = tid & 63;
    const int wave = tid >> 6;
    const int syy  = wave >> 1;
    const int sxp  = wave & 1;

    const float y1 = rois[roi * 4 + 0];
    const float x1 = rois[roi * 4 + 1];
    const float y2 = rois[roi * 4 + 2];
    const float x2 = rois[roi * 4 + 3];

    const float hh = y2 - y1 + 1.0f;
    const float ww = x2 - x1 + 1.0f;
    float lvlf = floorf(logf(sqrtf(hh * ww) / 224.0f) / 0.693147f + 4.0f);
    lvlf = fminf(fmaxf(lvlf, 2.0f), 5.0f);
    const int lvl = (int)lvlf;

    const _Float16* f;
    int H;
    if (lvl == 2)      { f = fT + OFF_T2; H = 256; }
    else if (lvl == 3) { f = fT + OFF_T3; H = 128; }
    else if (lvl == 4) { f = fT + OFF_T4; H = 64;  }
    else               { f = fT + OFF_T5; H = 32;  }
    const int W = H;

    const float imh = (float)img_size[0] - 1.0f;
    const float imw = (float)img_size[1] - 1.0f;
    const float r0 = y1 * (float)(H - 1) / imh;
    const float r1 = x1 * (float)(W - 1) / imw;
    const float r2 = y2 * (float)(H - 1) / imh;
    const float r3 = x2 * (float)(W - 1) / imw;
    const float hs  = (r2 - r0) * (1.0f / 14.0f);
    const float wst = (r3 - r1) * (1.0f / 14.0f);

    const float cy = ((float)(ph * 2 + syy) + 0.5f) * hs + r0;
    const float fy = floorf(cy);
    int   iu  = (int)fy;
    int   idn = (int)ceilf(cy);
    const float ly = cy - fy;
    iu  = min(max(iu, 0),  H - 1);
    idn = min(max(idn, 0), H - 1);
    const float wU = 1.0f - ly, wD = ly;
    const f16x4* rowU = (const f16x4*)(f + (size_t)(iu  * W) * 256);
    const f16x4* rowD = (const f16x4*)(f + (size_t)(idn * W) * 256);

    float4 (*red)[7][64] = reinterpret_cast<float4 (*)[7][64]>(smemc);   // 28 KB

#pragma unroll
    for (int pw = 0; pw < 7; ++pw) {
        const int sx = pw * 2 + sxp;
        const float cx = ((float)sx + 0.5f) * wst + r1;
        const float fx = floorf(cx);
        int   il = (int)fx;
        int   ir = (int)ceilf(cx);
        const float lx = cx - fx;
        il = min(max(il, 0), W - 1);
        ir = min(max(ir, 0), W - 1);

        const f16x4 h00 = rowU[il * 64 + lane];
        const f16x4 h01 = rowU[ir * 64 + lane];
        const f16x4 h10 = rowD[il * 64 + lane];
        const f16x4 h11 = rowD[ir * 64 + lane];
        const float lxm = 1.0f - lx;
        float4 v;
        v.x = ((float)h00.x * lxm + (float)h01.x * lx) * wU + ((float)h10.x * lxm + (float)h11.x * lx) * wD;
        v.y = ((float)h00.y * lxm + (float)h01.y * lx) * wU + ((float)h10.y * lxm + (float)h11.y * lx) * wD;
        v.z = ((float)h00.z * lxm + (float)h01.z * lx) * wU + ((float)h10.z * lxm + (float)h11.z * lx) * wD;
        v.w = ((float)h00.w * lxm + (float)h01.w * lx) * wU + ((float)h10.w * lxm + (float)h11.w * lx) * wD;
        red[wave][pw][lane] = v;
    }
    __syncthreads();

    for (int idx = tid; idx < 448; idx += 256) {
        const int pw = idx >> 6, cg = idx & 63;
        const float4 a = red[0][pw][cg];
        const float4 b = red[1][pw][cg];
        const float4 c = red[2][pw][cg];
        const float4 d = red[3][pw][cg];
        union { _Float16 h[4]; uint2 v2; } pk;
        pk.h[0] = (_Float16)fmaxf(fmaxf(a.x, b.x), fmaxf(c.x, d.x));
        pk.h[1] = (_Float16)fmaxf(fmaxf(a.y, b.y), fmaxf(c.y, d.y));
        pk.h[2] = (_Float16)fmaxf(fmaxf(a.z, b.z), fmaxf(c.z, d.z));
        pk.h[3] = (_Float16)fmaxf(fmaxf(a.w, b.w), fmaxf(c.w, d.w));
        _Float16* outp = pooledH + (size_t)roi * PD + (ph * 7 + pw) * 256 + cg * 4;
        *reinterpret_cast<uint2*>(outp) = pk.v2;
    }
}

// fp16 MFMA GEMM unit (proven 64x128/BK=64 structure). One block-unit.
__device__ __forceinline__ void gemm_unit(
    const unsigned short* __restrict__ A, const unsigned short* __restrict__ B,
    float* __restrict__ partial, int K2, int N,
    int z, int nz, int ny, int mz, char* smemc, int tid)
{
    unsigned short* As = reinterpret_cast<unsigned short*>(smemc);          // 8 KB
    unsigned short* Bs = reinterpret_cast<unsigned short*>(smemc + 8192);   // 16 KB

    const int lane = tid & 63;
    const int wave = tid >> 6;

    const int totalSteps = K2 >> 6;
    const int q = totalSteps / nz, r = totalSteps % nz;
    const int myStart = z * q + min(z, r);
    const int mySteps = q + (z < r ? 1 : 0);

    const int n0 = ny * 128;
    const int m0 = mz * 64;

    const int rIn  = lane >> 3;
    const int cSrc = (lane & 7) ^ rIn;
    const int mrow = lane & 15, quad = lane >> 4;

    floatx4 acc[8];
#pragma unroll
    for (int j = 0; j < 8; ++j)
        acc[j] = (floatx4){0.f, 0.f, 0.f, 0.f};

    for (int s = 0; s < mySteps; ++s) {
        const int k0 = (myStart + s) * 64;
#pragma unroll
        for (int qq = 0; qq < 2; ++qq) {
            const int rowBase = wave * 16 + qq * 8;
            const unsigned short* ga =
                A + (size_t)(m0 + rowBase + rIn) * K2 + k0 + cSrc * 8;
            __builtin_amdgcn_global_load_lds(
                (const __attribute__((address_space(1))) void*)ga,
                (__attribute__((address_space(3))) void*)&As[rowBase * 64], 16, 0, 0);
        }
#pragma unroll
        for (int qq = 0; qq < 4; ++qq) {
            const int rowBase = wave * 32 + qq * 8;
            const unsigned short* gb =
                B + (size_t)(n0 + rowBase + rIn) * K2 + k0 + cSrc * 8;
            __builtin_amdgcn_global_load_lds(
                (const __attribute__((address_space(1))) void*)gb,
                (__attribute__((address_space(3))) void*)&Bs[rowBase * 64], 16, 0, 0);
        }
        __syncthreads();

#pragma unroll
        for (int ks = 0; ks < 2; ++ks) {
            const int ra = wave * 16 + mrow;
            const int ca = ((ks * 4 + quad) ^ (ra & 7)) * 8;
            const f16x8 aF = *reinterpret_cast<const f16x8*>(&As[ra * 64 + ca]);
#pragma unroll
            for (int j = 0; j < 8; ++j) {
                const int rb = j * 16 + mrow;
                const int cb = ((ks * 4 + quad) ^ (rb & 7)) * 8;
                const f16x8 bF = *reinterpret_cast<const f16x8*>(&Bs[rb * 64 + cb]);
                acc[j] = __builtin_amdgcn_mfma_f32_16x16x32_f16(aF, bF, acc[j], 0, 0, 0);
            }
        }
        __syncthreads();
    }

    // slice stride: 16 m-blocks x 64 rows = 1024 rows x N
    float* p = partial + (size_t)z * (size_t)(16 * 64) * N;
    const int row = m0 + wave * 16 + quad * 4;
#pragma unroll
    for (int j = 0; j < 8; ++j) {
        const int col = n0 + j * 16 + mrow;
#pragma unroll
        for (int rr = 0; rr < 4; ++rr)
            p[(size_t)(row + rr) * N + col] = acc[j][rr];
    }
}

__device__ __forceinline__ void red_fc_unit(
    int b, const float* __restrict__ partial, const float* __restrict__ bias,
    _Float16* __restrict__ outH, int nz, int tid)
{
    const int i4 = b * 256 + tid;
    const int off = i4 * 4;
    const int n = off & 1023;
    float4 acc = *reinterpret_cast<const float4*>(partial + off);
    for (int z = 1; z < nz; ++z) {
        const float4 v = *reinterpret_cast<const float4*>(
            partial + (size_t)z * 1024 * 1024 + off);
        acc.x += v.x; acc.y += v.y; acc.z += v.z; acc.w += v.w;
    }
    const float4 bv = *reinterpret_cast<const float4*>(bias + n);
    union { _Float16 h[4]; uint2 u2; } pk;
    pk.h[0] = (_Float16)fmaxf(acc.x + bv.x, 0.f);
    pk.h[1] = (_Float16)fmaxf(acc.y + bv.y, 0.f);
    pk.h[2] = (_Float16)fmaxf(acc.z + bv.z, 0.f);
    pk.h[3] = (_Float16)fmaxf(acc.w + bv.w, 0.f);
    *reinterpret_cast<uint2*>(outH + off) = pk.u2;
}

__device__ __forceinline__ void red_heads_unit(
    int m, const float* __restrict__ partial, const float* __restrict__ bloc,
    const float* __restrict__ bsc, float* __restrict__ out0,
    float* __restrict__ out1, int nz, int tid)
{
    for (int n = tid; n < NH; n += 256) {
        float s = 0.f;
        for (int z = 0; z < nz; ++z)
            s += partial[(size_t)z * 1024 * 512 + (size_t)m * 512 + n];
        if (n < NLOC) out0[(size_t)m * NLOC + n] = s + bloc[n];
        else          out1[(size_t)m * NSC + (n - NLOC)] = s + bsc[n - NLOC];
    }
}

// ===========================================================================
// Mega kernel: whole pipeline, one NORMAL launch, 1024 blocks x 256,
// software ticket barrier (tid0-only cache maintenance) between phases.
// ===========================================================================
__global__ __launch_bounds__(256, 4) void mega_kernel(
    const float* __restrict__ f2, const float* __restrict__ f3,
    const float* __restrict__ f4, const float* __restrict__ f5,
    const float* __restrict__ rois, const int* __restrict__ img,
    const float* __restrict__ W1, const float* __restrict__ b1,
    const float* __restrict__ W2, const float* __restrict__ b2,
    const float* __restrict__ Wloc, const float* __restrict__ bloc,
    const float* __restrict__ Wsc, const float* __restrict__ bsc,
    float* __restrict__ out, float* __restrict__ ws)
{
    __shared__ __align__(16) char smem[28672];
    const int tid = threadIdx.x;
    const int nb  = gridDim.x;      // 1024

    _Float16* fT     = (_Float16*)(ws + OFF_FT);
    _Float16* pooled = (_Float16*)(ws + OFF_POOL);
    _Float16* w1t    = (_Float16*)(ws + OFF_W1T);
    float*    part1  = ws + OFF_PART1;
    float*    part2  = ws + OFF_PART2;
    _Float16* fc1    = (_Float16*)(ws + OFF_FC1);
    _Float16* w2t    = (_Float16*)(ws + OFF_W2T);
    _Float16* wht    = (_Float16*)(ws + OFF_WHT);
    _Float16* fc2    = (_Float16*)(ws + OFF_FC2);
    float*    out0   = out;
    float*    out1   = out + (size_t)NROIS * NLOC;

    // ---- Phase A: transpose (5440) + W1 (3136) + W2 (256) + Wh (128) ----
    for (int u = blockIdx.x; u < 8960; u += nb) {
        if (u < 5440)      transpose_unit(u, f2, f3, f4, f5, fT, smem, tid);
        else if (u < 8576) w1_unit(u - 5440, W1, w1t, smem, tid);
        else if (u < 8832) w2_unit(u - 8576, W2, w2t, smem, tid);
        else               wh_unit(u - 8832, Wloc, Wsc, wht, smem, tid);
        __syncthreads();
    }
    grid_barrier(tid);

    // ---- Phase B: ROI pool (7000 units) ----
    for (int u = blockIdx.x; u < 7000; u += nb) {
        pool_unit(u, fT, rois, img, pooled, smem, tid);
        __syncthreads();
    }
    grid_barrier(tid);

    // ---- Phase C: fc1 GEMM (z=8, ny=8, mz=16) = 1024 units exact ----
    {
        const int b = blockIdx.x;
        gemm_unit((const unsigned short*)pooled, (const unsigned short*)w1t,
                  part1, PD, 1024, b & 7, 8, (b >> 3) & 7, b >> 6, smem, tid);
    }
    grid_barrier(tid);

    // ---- Phase D: red1 -> fc1 ----
    red_fc_unit(blockIdx.x, part1, b1, fc1, 8, tid);
    grid_barrier(tid);

    // ---- Phase E: fc2 GEMM (z=8, ny=8, mz=16) ----
    {
        const int b = blockIdx.x;
        gemm_unit((const unsigned short*)fc1, (const unsigned short*)w2t,
                  part2, KFC, 1024, b & 7, 8, (b >> 3) & 7, b >> 6, smem, tid);
    }
    grid_barrier(tid);

    // ---- Phase F: red2 -> fc2 ----
    red_fc_unit(blockIdx.x, part2, b2, fc2, 8, tid);
    grid_barrier(tid);

    // ---- Phase G: heads GEMM (z=16, ny=4, mz=16), N=512 ----
    {
        const int b = blockIdx.x;
        gemm_unit((const unsigned short*)fc2, (const unsigned short*)wht,
                  part2, KFC, 512, b & 15, 16, (b >> 4) & 3, b >> 6, smem, tid);
    }
    grid_barrier(tid);

    // ---- Phase H: heads reduction ----
    if (blockIdx.x < NROIS)
        red_heads_unit(blockIdx.x, part2, bloc, bsc, out0, out1, 16, tid);
}

// ---------------------------------------------------------------------------
extern "C" void kernel_launch(void* const* d_in, const int* in_sizes, int n_in,
                              void* d_out, int out_size, void* d_ws, size_t ws_size,
                              hipStream_t stream)
{
    const float* f2   = (const float*)d_in[0];
    const float* f3   = (const float*)d_in[1];
    const float* f4   = (const float*)d_in[2];
    const float* f5   = (const float*)d_in[3];
    const float* rois = (const float*)d_in[4];
    const int*   img  = (const int*)d_in[5];
    const float* W1   = (const float*)d_in[6];
    const float* b1   = (const float*)d_in[7];
    const float* W2   = (const float*)d_in[8];
    const float* b2   = (const float*)d_in[9];
    const float* Wloc = (const float*)d_in[10];
    const float* bloc = (const float*)d_in[11];
    const float* Wsc  = (const float*)d_in[12];
    const float* bsc  = (const float*)d_in[13];
    float* out = (float*)d_out;
    float* ws  = (float*)d_ws;

    mega_kernel<<<dim3(NBLK), dim3(256), 0, stream>>>(
        f2, f3, f4, f5, rois, img, W1, b1, W2, b2,
        Wloc, bloc, Wsc, bsc, out, ws);
}